// Round 1
// baseline (585.093 us; speedup 1.0000x reference)
//
#include <hip/hip_runtime.h>
#include <math.h>

#define N_WIRES 12
#define DEPTH   4
#define IN_DIM  256
#define NSTATE  4096   // 2^12
#define BLOCK   256

struct GateTables {
    unsigned int mask[DEPTH][N_WIRES];   // XOR mask pairing stored indices
    unsigned int sel [DEPTH][N_WIRES];   // branch selector (parity -> role)
    unsigned int selF[N_WIRES];          // final <Z_w> sign selector (row w of L^4)
};

__global__ __launch_bounds__(BLOCK)
void varsim_kernel(const float* __restrict__ x, const float* __restrict__ W,
                   const float* __restrict__ params, float* __restrict__ out,
                   GateTables gt)
{
    __shared__ __align__(16) float sre[NSTATE];
    __shared__ __align__(16) float sim_[NSTATE];
    __shared__ float s_c0[N_WIRES], s_s0[N_WIRES];
    __shared__ float s_cp[DEPTH * N_WIRES], s_sp[DEPTH * N_WIRES];
    __shared__ float red[N_WIRES][4];

    const int t    = threadIdx.x;
    const int b    = blockIdx.x;
    const int lane = t & 63;
    const int wv   = t >> 6;

    // ---- angles[w] = dot(x[b,:], W[w,:]) ; IN_DIM == BLOCK == 256 ----
    float xv = x[(size_t)b * IN_DIM + t];
    #pragma unroll
    for (int w = 0; w < N_WIRES; ++w) {
        float p = xv * W[w * IN_DIM + t];
        #pragma unroll
        for (int o = 32; o > 0; o >>= 1) p += __shfl_down(p, o, 64);
        if (lane == 0) red[w][wv] = p;
    }
    __syncthreads();
    if (t < N_WIRES) {
        float ang = red[t][0] + red[t][1] + red[t][2] + red[t][3];
        float sh, ch;
        sincosf(0.5f * ang, &sh, &ch);
        s_c0[t] = ch; s_s0[t] = sh;
    }
    if (t >= 64 && t < 64 + DEPTH * N_WIRES) {
        int g = t - 64;
        float sh, ch;
        sincosf(0.5f * params[g], &sh, &ch);
        s_cp[g] = ch; s_sp[g] = sh;
    }
    __syncthreads();

    // ---- init product state: amp[j] = (-i)^popc(j) * prod_w (bit? s : c) ----
    float c0r[N_WIRES], s0r[N_WIRES];
    #pragma unroll
    for (int w = 0; w < N_WIRES; ++w) { c0r[w] = s_c0[w]; s0r[w] = s_s0[w]; }
    #pragma unroll 1
    for (int k = 0; k < 16; ++k) {
        int j = t * 16 + k;
        float m = 1.0f;
        #pragma unroll
        for (int w = 0; w < N_WIRES; ++w)
            m *= ((j >> w) & 1) ? s0r[w] : c0r[w];
        int pc = __popc(j) & 3;
        float rr = (pc == 0) ? m : ((pc == 2) ? -m : 0.0f);
        float ii = (pc == 1) ? -m : ((pc == 3) ? m : 0.0f);
        sre[j] = rr; sim_[j] = ii;
    }
    __syncthreads();

    // ---- 4 layers x 12 RX butterflies (CNOT chains folded into masks/sels) ----
    for (int d = 0; d < DEPTH; ++d) {
        for (int w = 0; w < N_WIRES; ++w) {
            const unsigned mask = gt.mask[d][w];
            const unsigned sel  = gt.sel[d][w];
            const float c = s_cp[d * N_WIRES + w];
            const float s = s_sp[d * N_WIRES + w];

            if ((mask & 3u) == 0u) {
                // vector path: 4 consecutive pairs, both sides 4-aligned
                const unsigned pi   = 31 - __clz(mask);      // msb of mask
                const unsigned lowm = (1u << pi) - 1u;
                for (int g = t; g < 512; g += BLOCK) {
                    unsigned p4 = (unsigned)g * 4u;
                    unsigned b0 = ((p4 & ~lowm) << 1) | (p4 & lowm);
                    unsigned b1 = b0 ^ mask;
                    float4 r0 = *(const float4*)&sre[b0];
                    float4 i0 = *(const float4*)&sim_[b0];
                    float4 r1 = *(const float4*)&sre[b1];
                    float4 i1 = *(const float4*)&sim_[b1];
                    float4 R0, I0, R1, I1;
                    #pragma unroll
                    for (int k = 0; k < 4; ++k) {
                        float a0r = ((const float*)&r0)[k], a0i = ((const float*)&i0)[k];
                        float a1r = ((const float*)&r1)[k], a1i = ((const float*)&i1)[k];
                        unsigned j0 = b0 + (unsigned)k;
                        bool sw = (__popc(j0 & sel) & 1) != 0;
                        float u0r = sw ? a1r : a0r, u0i = sw ? a1i : a0i;
                        float u1r = sw ? a0r : a1r, u1i = sw ? a0i : a1i;
                        float v0r = c * u0r + s * u1i;
                        float v0i = c * u0i - s * u1r;
                        float v1r = c * u1r + s * u0i;
                        float v1i = c * u1i - s * u0r;
                        ((float*)&R0)[k] = sw ? v1r : v0r;
                        ((float*)&I0)[k] = sw ? v1i : v0i;
                        ((float*)&R1)[k] = sw ? v0r : v1r;
                        ((float*)&I1)[k] = sw ? v0i : v1i;
                    }
                    *(float4*)&sre[b0] = R0; *(float4*)&sim_[b0] = I0;
                    *(float4*)&sre[b1] = R1; *(float4*)&sim_[b1] = I1;
                }
            } else {
                // scalar path (masks touching bits 0/1): 8 pairs per thread
                const unsigned pi   = (unsigned)__ffs((int)mask) - 1u;
                const unsigned lowm = (1u << pi) - 1u;
                #pragma unroll
                for (int r = 0; r < NSTATE / 2 / BLOCK; ++r) {
                    unsigned p  = (unsigned)(r * BLOCK + t);
                    unsigned j0 = ((p & ~lowm) << 1) | (p & lowm);
                    unsigned j1 = j0 ^ mask;
                    float a0r = sre[j0], a0i = sim_[j0];
                    float a1r = sre[j1], a1i = sim_[j1];
                    bool sw = (__popc(j0 & sel) & 1) != 0;
                    float u0r = sw ? a1r : a0r, u0i = sw ? a1i : a0i;
                    float u1r = sw ? a0r : a1r, u1i = sw ? a0i : a1i;
                    float v0r = c * u0r + s * u1i;
                    float v0i = c * u0i - s * u1r;
                    float v1r = c * u1r + s * u0i;
                    float v1i = c * u1i - s * u0r;
                    sre[j0] = sw ? v1r : v0r; sim_[j0] = sw ? v1i : v0i;
                    sre[j1] = sw ? v0r : v1r; sim_[j1] = sw ? v0i : v1i;
                }
            }
            __syncthreads();
        }
    }

    // ---- measure <Z_w> = sum_j |amp_j|^2 * (-1)^parity(selF[w] & j) ----
    float acc[N_WIRES];
    #pragma unroll
    for (int w = 0; w < N_WIRES; ++w) acc[w] = 0.0f;
    #pragma unroll 1
    for (int k4 = 0; k4 < 4; ++k4) {
        int j = t * 16 + k4 * 4;
        float4 r  = *(const float4*)&sre[j];
        float4 i4 = *(const float4*)&sim_[j];
        #pragma unroll
        for (int k = 0; k < 4; ++k) {
            float rr = ((float*)&r)[k], ii = ((float*)&i4)[k];
            float pr = rr * rr + ii * ii;
            int jj = j + k;
            #pragma unroll
            for (int w = 0; w < N_WIRES; ++w)
                acc[w] += (__popc(jj & (int)gt.selF[w]) & 1) ? -pr : pr;
        }
    }
    __syncthreads();
    #pragma unroll
    for (int w = 0; w < N_WIRES; ++w) {
        float p = acc[w];
        #pragma unroll
        for (int o = 32; o > 0; o >>= 1) p += __shfl_down(p, o, 64);
        if (lane == 0) red[w][wv] = p;
    }
    __syncthreads();
    if (t < N_WIRES)
        out[(size_t)b * N_WIRES + t] = red[t][0] + red[t][1] + red[t][2] + red[t][3];
}

// ---- host-side GF(2) setup: CNOT chain as linear map L, track M = L^d ----
static void gf2_mul(const unsigned* A, const unsigned* B, unsigned* C) {
    for (int i = 0; i < N_WIRES; ++i) {
        unsigned r = 0;
        for (int v = 0; v < N_WIRES; ++v)
            if ((A[i] >> v) & 1) r ^= B[v];
        C[i] = r;
    }
}

extern "C" void kernel_launch(void* const* d_in, const int* in_sizes, int n_in,
                              void* d_out, int out_size, void* d_ws, size_t ws_size,
                              hipStream_t stream) {
    const float* x      = (const float*)d_in[0];
    const float* W      = (const float*)d_in[1];
    const float* params = (const float*)d_in[2];
    float* out          = (float*)d_out;

    // L: b'_w = b_0 ^ ... ^ b_w ; Linv: b_w = b'_w ^ b'_{w-1}
    unsigned L[N_WIRES], Linv[N_WIRES];
    for (int w = 0; w < N_WIRES; ++w) {
        L[w] = (1u << (w + 1)) - 1u;
        Linv[w] = (w == 0) ? 1u : ((1u << w) | (1u << (w - 1)));
    }
    unsigned Mp[DEPTH + 1][N_WIRES], Mi[DEPTH + 1][N_WIRES];
    for (int w = 0; w < N_WIRES; ++w) { Mp[0][w] = 1u << w; Mi[0][w] = 1u << w; }
    for (int d = 1; d <= DEPTH; ++d) {
        gf2_mul(L, Mp[d - 1], Mp[d]);
        gf2_mul(Linv, Mi[d - 1], Mi[d]);
    }

    GateTables gt;
    for (int d = 0; d < DEPTH; ++d)
        for (int w = 0; w < N_WIRES; ++w) {
            unsigned m = 0;
            for (int u = 0; u < N_WIRES; ++u)
                if ((Mi[d][u] >> w) & 1) m |= (1u << u);   // column w of L^-d
            gt.mask[d][w] = m;
            gt.sel[d][w]  = Mp[d][w];                       // row w of L^d
        }
    for (int w = 0; w < N_WIRES; ++w) gt.selF[w] = Mp[DEPTH][w];

    int batch = in_sizes[0] / IN_DIM;
    hipLaunchKernelGGL(varsim_kernel, dim3(batch), dim3(BLOCK), 0, stream,
                       x, W, params, out, gt);
}

// Round 2
// 82.065 us; speedup vs baseline: 7.1296x; 7.1296x over previous
//
#include <hip/hip_runtime.h>
#include <math.h>

#define N_WIRES 12
#define DEPTH   4
#define IN_DIM  256
#define NK      4096      // 2^12 phase classes
#define ROWS_PER_BLOCK 16
#define XSTRIDE 272       // 256 + 16 pad -> 2-way max bank aliasing (free)

// All gates are exp(-i theta/2 * X_string) after folding the CNOT chains
// (CNOT conjugation keeps X-strings X-type). They all commute and are
// diagonal in the Hadamard basis where |0..0> is uniform:
//   <Z_S> = 2^-n sum_k cos( sum_{g: par(m_g&S)=1} theta_g * (-1)^par(m_g&k) )
// Param-gate part collapses to C/D[w][kappa] constants (kernel 1);
// batch part is B = sum_{w' in S} (+-) ang_{b,w'} with kappa = bits of k on S
// (kernel 2): out = (1/4096) sum_kappa cos(B)*C - sin(B)*D.

struct MaskTable {
    unsigned m[DEPTH * N_WIRES];   // mask of param gate (d,w) = col w of L^-d
    unsigned S[N_WIRES];           // measurement Z-string: row w of L^4
};

__global__ __launch_bounds__(256)
void consts_kernel(const float* __restrict__ params, float* __restrict__ ws,
                   MaskTable mt)
{
    const int w = blockIdx.x;
    const int t = threadIdx.x;
    __shared__ float    thA[DEPTH * N_WIRES];
    __shared__ unsigned mAs[DEPTH * N_WIRES];
    __shared__ int      naS;
    __shared__ float    red[4][16];

    if (t == 0) {   // gather gates with par(m & S) == 1
        int na = 0;
        unsigned S = mt.S[w];
        for (int g = 0; g < DEPTH * N_WIRES; ++g)
            if (__popc(mt.m[g] & S) & 1) { mAs[na] = mt.m[g]; thA[na] = params[g]; ++na; }
        naS = na;
    }
    __syncthreads();
    const int na = naS;
    const unsigned S = mt.S[w];
    int pos[3], nb = 0;
    for (int b = 0; b < N_WIRES; ++b) if ((S >> b) & 1) pos[nb++] = b;

    float acc[16];   // [0..7] = sum cos(P) per kappa, [8..15] = sum sin(P)
    #pragma unroll
    for (int c = 0; c < 16; ++c) acc[c] = 0.f;

    for (int i = 0; i < 16; ++i) {
        int k = (i << 8) | t;
        float P = 0.f;
        for (int g = 0; g < na; ++g) {
            float sgn = 1.f - 2.f * (float)(__popc(mAs[g] & (unsigned)k) & 1);
            P = fmaf(sgn, thA[g], P);
        }
        float sn, cs;
        sincosf(P, &sn, &cs);
        int kap = 0;
        for (int j = 0; j < nb; ++j) kap |= ((k >> pos[j]) & 1) << j;
        #pragma unroll
        for (int c = 0; c < 8; ++c) {
            acc[c]     += (c == kap) ? cs : 0.f;
            acc[c + 8] += (c == kap) ? sn : 0.f;
        }
    }
    #pragma unroll
    for (int c = 0; c < 16; ++c) {
        float v = acc[c];
        #pragma unroll
        for (int o = 1; o < 64; o <<= 1) v += __shfl_xor(v, o, 64);
        acc[c] = v;
    }
    const int lane = t & 63, wv = t >> 6;
    if (lane == 0)
        #pragma unroll
        for (int c = 0; c < 16; ++c) red[wv][c] = acc[c];
    __syncthreads();
    if (t < 16)
        ws[w * 16 + t] = red[0][t] + red[1][t] + red[2][t] + red[3][t];
}

__global__ __launch_bounds__(256)
void batch_kernel(const float* __restrict__ x, const float* __restrict__ W,
                  const float* __restrict__ ws, float* __restrict__ out,
                  MaskTable mt)
{
    __shared__ float xl[ROWS_PER_BLOCK * XSTRIDE];
    __shared__ float wl[N_WIRES * IN_DIM];
    __shared__ float al[ROWS_PER_BLOCK * N_WIRES];
    __shared__ float cl[N_WIRES * 16];
    const int t = threadIdx.x;
    const int rowbase = blockIdx.x * ROWS_PER_BLOCK;

    // stage x tile (16 rows x 256 fp32), padded row stride
    const float4* x4 = (const float4*)(x + (size_t)rowbase * IN_DIM);
    #pragma unroll
    for (int j = 0; j < 4; ++j) {
        int f   = t + 256 * j;     // 0..1023 float4s
        int row = f >> 6;          // 64 float4 per row
        int c4  = f & 63;
        float4 v = x4[f];
        *(float4*)&xl[row * XSTRIDE + c4 * 4] = v;
    }
    const float4* W4 = (const float4*)W;
    #pragma unroll
    for (int j = 0; j < 3; ++j) {
        int f = t + 256 * j;       // 0..767
        ((float4*)wl)[f] = W4[f];
    }
    if (t < N_WIRES * 16) cl[t] = ws[t];
    __syncthreads();

    // angles: 16 threads per row, 16 elems each, xor-shuffle reduce
    const int r = t >> 4, p = t & 15;
    float partial[N_WIRES];
    #pragma unroll
    for (int w = 0; w < N_WIRES; ++w) partial[w] = 0.f;
    for (int i = 0; i < 16; ++i) {
        float xv = xl[r * XSTRIDE + i * 16 + p];
        #pragma unroll
        for (int w = 0; w < N_WIRES; ++w)
            partial[w] = fmaf(xv, wl[w * IN_DIM + i * 16 + p], partial[w]);
    }
    #pragma unroll
    for (int w = 0; w < N_WIRES; ++w) {
        float v = partial[w];
        v += __shfl_xor(v, 1, 16);
        v += __shfl_xor(v, 2, 16);
        v += __shfl_xor(v, 4, 16);
        v += __shfl_xor(v, 8, 16);
        partial[w] = v;
    }
    if (p < N_WIRES) al[r * N_WIRES + p] = partial[p];
    __syncthreads();

    // outputs: one thread per (row, wire)
    if (t < ROWS_PER_BLOCK * N_WIRES) {
        const int r2 = t / N_WIRES;
        const int w  = t - r2 * N_WIRES;
        unsigned S = mt.S[w];
        int pos[3], nb = 0;
        for (int b = 0; b < N_WIRES; ++b) if ((S >> b) & 1) pos[nb++] = b;
        float a[3] = {0.f, 0.f, 0.f};
        for (int j = 0; j < nb; ++j) a[j] = al[r2 * N_WIRES + pos[j]];
        float o = 0.f;
        const int nk = 1 << nb;
        for (int kap = 0; kap < nk; ++kap) {
            float B = 0.f;
            for (int j = 0; j < nb; ++j)
                B += ((kap >> j) & 1) ? -a[j] : a[j];
            float sn, cs;
            sincosf(B, &sn, &cs);
            o = fmaf(cs,  cl[w * 16 + kap],     o);
            o = fmaf(-sn, cl[w * 16 + 8 + kap], o);
        }
        out[(size_t)(rowbase + r2) * N_WIRES + w] = o * (1.f / 4096.f);
    }
}

// ---- host-side GF(2): CNOT chain as linear map L over index bits ----
static void gf2_mul(const unsigned* A, const unsigned* B, unsigned* C) {
    for (int i = 0; i < N_WIRES; ++i) {
        unsigned r = 0;
        for (int v = 0; v < N_WIRES; ++v)
            if ((A[i] >> v) & 1) r ^= B[v];
        C[i] = r;
    }
}

extern "C" void kernel_launch(void* const* d_in, const int* in_sizes, int n_in,
                              void* d_out, int out_size, void* d_ws, size_t ws_size,
                              hipStream_t stream) {
    const float* x      = (const float*)d_in[0];
    const float* W      = (const float*)d_in[1];
    const float* params = (const float*)d_in[2];
    float* out          = (float*)d_out;
    float* wsf          = (float*)d_ws;

    unsigned L[N_WIRES], Linv[N_WIRES];
    for (int w = 0; w < N_WIRES; ++w) {
        L[w]    = (1u << (w + 1)) - 1u;
        Linv[w] = (w == 0) ? 1u : ((1u << w) | (1u << (w - 1)));
    }
    unsigned Mp[DEPTH + 1][N_WIRES], Mi[DEPTH + 1][N_WIRES];
    for (int w = 0; w < N_WIRES; ++w) { Mp[0][w] = 1u << w; Mi[0][w] = 1u << w; }
    for (int d = 1; d <= DEPTH; ++d) {
        gf2_mul(L, Mp[d - 1], Mp[d]);
        gf2_mul(Linv, Mi[d - 1], Mi[d]);
    }

    MaskTable mt;
    for (int d = 0; d < DEPTH; ++d)
        for (int w = 0; w < N_WIRES; ++w) {
            unsigned m = 0;
            for (int u = 0; u < N_WIRES; ++u)
                if ((Mi[d][u] >> w) & 1) m |= (1u << u);   // column w of L^-d
            mt.m[d * N_WIRES + w] = m;
        }
    for (int w = 0; w < N_WIRES; ++w) mt.S[w] = Mp[DEPTH][w];

    const int batch = in_sizes[0] / IN_DIM;

    hipLaunchKernelGGL(consts_kernel, dim3(N_WIRES), dim3(256), 0, stream,
                       params, wsf, mt);
    hipLaunchKernelGGL(batch_kernel, dim3(batch / ROWS_PER_BLOCK), dim3(256), 0, stream,
                       x, W, wsf, out, mt);
}

// Round 3
// 75.389 us; speedup vs baseline: 7.7609x; 1.0886x over previous
//
#include <hip/hip_runtime.h>
#include <math.h>

#define N_WIRES 12
#define DEPTH   4
#define NGATES  (DEPTH * N_WIRES)   // 48
#define IN_DIM  256
#define ROWS_PER_BLOCK 16
#define XSTRIDE 272                 // 256 + 16 pad
#define K_BLOCKS 16                 // consts kernel grid

// All gates are exp(-i theta/2 * X_string) after folding the CNOT chains
// (CNOT conjugation keeps X-strings X-type; verified empirically in R1/R2).
// All commute, diagonal in Hadamard basis where |0..0> is uniform:
//   <Z_S> = 2^-n sum_k cos( sum_{g: par(m_g&S)=1} theta_g * (-1)^par(m_g&k) )
// Split param gates (batch-independent -> C/D[w][kappa] constants, kernel 1,
// 16 partial tables) from encoding gates (kernel 2):
//   out = (1/4096) sum_kappa cos(B)*C[kappa] - sin(B)*D[kappa],
//   B = sum_{w' in S} (+-) ang_{b,w'}, kappa = k-bits of S positions.

struct ConstTab {
    unsigned m[NGATES];              // gate masks: col w of L^-d
    float    wt[N_WIRES][NGATES];    // 1.0 iff par(m_g & S_w) == 1
    unsigned sh[N_WIRES][3];         // kappa bit shifts (31 = unused -> 0)
};
struct MeasTab {
    unsigned S[N_WIRES];             // measurement Z-string: row w of L^4
};

__global__ __launch_bounds__(256)
void consts_kernel(const float* __restrict__ params, float* __restrict__ ws,
                   ConstTab ct)
{
    __shared__ float acc[N_WIRES * 16];
    const int t = threadIdx.x;
    if (t < N_WIRES * 16) acc[t] = 0.f;
    __syncthreads();

    const unsigned k = blockIdx.x * 256u + (unsigned)t;

    float th[NGATES];
    #pragma unroll
    for (int g = 0; g < NGATES; ++g) th[g] = params[g];   // uniform -> s_load

    float P[N_WIRES];
    #pragma unroll
    for (int w = 0; w < N_WIRES; ++w) P[w] = 0.f;

    #pragma unroll
    for (int g = 0; g < NGATES; ++g) {
        unsigned par = (unsigned)(__popc(ct.m[g] & k) & 1);
        float sg = __int_as_float(__float_as_int(th[g]) ^ (int)(par << 31));
        #pragma unroll
        for (int w = 0; w < N_WIRES; ++w)
            P[w] = fmaf(sg, ct.wt[w][g], P[w]);
    }

    #pragma unroll
    for (int w = 0; w < N_WIRES; ++w) {
        float sn, cs;
        sincosf(P[w], &sn, &cs);
        unsigned kap =  ((k >> ct.sh[w][0]) & 1u)
                     | (((k >> ct.sh[w][1]) & 1u) << 1)
                     | (((k >> ct.sh[w][2]) & 1u) << 2);
        atomicAdd(&acc[w * 16 + kap], cs);
        atomicAdd(&acc[w * 16 + 8 + kap], sn);
    }
    __syncthreads();
    if (t < N_WIRES * 16)
        ws[blockIdx.x * (N_WIRES * 16) + t] = acc[t];
}

__global__ __launch_bounds__(256)
void batch_kernel(const float* __restrict__ x, const float* __restrict__ W,
                  const float* __restrict__ ws, float* __restrict__ out,
                  MeasTab mt)
{
    __shared__ float xl[ROWS_PER_BLOCK * XSTRIDE];
    __shared__ float wl[N_WIRES * IN_DIM];
    __shared__ float al[ROWS_PER_BLOCK * N_WIRES];
    __shared__ float cl[N_WIRES * 16];
    const int t = threadIdx.x;
    const int rowbase = blockIdx.x * ROWS_PER_BLOCK;

    // stage x tile (16 rows x 256 fp32), padded row stride
    const float4* x4 = (const float4*)(x + (size_t)rowbase * IN_DIM);
    #pragma unroll
    for (int j = 0; j < 4; ++j) {
        int f   = t + 256 * j;     // 0..1023 float4s
        int row = f >> 6;          // 64 float4 per row
        int c4  = f & 63;
        float4 v = x4[f];
        *(float4*)&xl[row * XSTRIDE + c4 * 4] = v;
    }
    const float4* W4 = (const float4*)W;
    #pragma unroll
    for (int j = 0; j < 3; ++j) {
        int f = t + 256 * j;       // 0..767
        ((float4*)wl)[f] = W4[f];
    }
    if (t < N_WIRES * 16) {        // sum the 16 partial constant tables
        float v = 0.f;
        #pragma unroll
        for (int p = 0; p < K_BLOCKS; ++p) v += ws[p * (N_WIRES * 16) + t];
        cl[t] = v;
    }
    __syncthreads();

    // angles: 16 threads per row, 16 elems each, xor-shuffle reduce
    const int r = t >> 4, p = t & 15;
    float partial[N_WIRES];
    #pragma unroll
    for (int w = 0; w < N_WIRES; ++w) partial[w] = 0.f;
    for (int i = 0; i < 16; ++i) {
        float xv = xl[r * XSTRIDE + i * 16 + p];
        #pragma unroll
        for (int w = 0; w < N_WIRES; ++w)
            partial[w] = fmaf(xv, wl[w * IN_DIM + i * 16 + p], partial[w]);
    }
    #pragma unroll
    for (int w = 0; w < N_WIRES; ++w) {
        float v = partial[w];
        v += __shfl_xor(v, 1, 16);
        v += __shfl_xor(v, 2, 16);
        v += __shfl_xor(v, 4, 16);
        v += __shfl_xor(v, 8, 16);
        partial[w] = v;
    }
    if (p < N_WIRES) al[r * N_WIRES + p] = partial[p];
    __syncthreads();

    // outputs: one thread per (row, wire)
    if (t < ROWS_PER_BLOCK * N_WIRES) {
        const int r2 = t / N_WIRES;
        const int w  = t - r2 * N_WIRES;
        unsigned S = mt.S[w];
        int pos[3], nb = 0;
        for (int b = 0; b < N_WIRES; ++b) if ((S >> b) & 1) pos[nb++] = b;
        float a[3] = {0.f, 0.f, 0.f};
        for (int j = 0; j < nb; ++j) a[j] = al[r2 * N_WIRES + pos[j]];
        float o = 0.f;
        const int nk = 1 << nb;
        for (int kap = 0; kap < nk; ++kap) {
            float B = 0.f;
            for (int j = 0; j < nb; ++j)
                B += ((kap >> j) & 1) ? -a[j] : a[j];
            float sn, cs;
            __sincosf(B, &sn, &cs);
            o = fmaf(cs,  cl[w * 16 + kap],     o);
            o = fmaf(-sn, cl[w * 16 + 8 + kap], o);
        }
        out[(size_t)(rowbase + r2) * N_WIRES + w] = o * (1.f / 4096.f);
    }
}

// ---- host-side GF(2): CNOT chain as linear map L over index bits ----
static void gf2_mul(const unsigned* A, const unsigned* B, unsigned* C) {
    for (int i = 0; i < N_WIRES; ++i) {
        unsigned r = 0;
        for (int v = 0; v < N_WIRES; ++v)
            if ((A[i] >> v) & 1) r ^= B[v];
        C[i] = r;
    }
}
static int popc_host(unsigned v) { int c = 0; while (v) { c += v & 1; v >>= 1; } return c; }

extern "C" void kernel_launch(void* const* d_in, const int* in_sizes, int n_in,
                              void* d_out, int out_size, void* d_ws, size_t ws_size,
                              hipStream_t stream) {
    const float* x      = (const float*)d_in[0];
    const float* W      = (const float*)d_in[1];
    const float* params = (const float*)d_in[2];
    float* out          = (float*)d_out;
    float* wsf          = (float*)d_ws;

    unsigned L[N_WIRES], Linv[N_WIRES];
    for (int w = 0; w < N_WIRES; ++w) {
        L[w]    = (1u << (w + 1)) - 1u;
        Linv[w] = (w == 0) ? 1u : ((1u << w) | (1u << (w - 1)));
    }
    unsigned Mp[DEPTH + 1][N_WIRES], Mi[DEPTH + 1][N_WIRES];
    for (int w = 0; w < N_WIRES; ++w) { Mp[0][w] = 1u << w; Mi[0][w] = 1u << w; }
    for (int d = 1; d <= DEPTH; ++d) {
        gf2_mul(L, Mp[d - 1], Mp[d]);
        gf2_mul(Linv, Mi[d - 1], Mi[d]);
    }

    ConstTab ct;
    MeasTab  mt;
    for (int d = 0; d < DEPTH; ++d)
        for (int w = 0; w < N_WIRES; ++w) {
            unsigned m = 0;
            for (int u = 0; u < N_WIRES; ++u)
                if ((Mi[d][u] >> w) & 1) m |= (1u << u);   // column w of L^-d
            ct.m[d * N_WIRES + w] = m;
        }
    for (int w = 0; w < N_WIRES; ++w) mt.S[w] = Mp[DEPTH][w];

    for (int w = 0; w < N_WIRES; ++w) {
        for (int g = 0; g < NGATES; ++g)
            ct.wt[w][g] = (popc_host(ct.m[g] & mt.S[w]) & 1) ? 1.f : 0.f;
        int nb = 0;
        for (int b = 0; b < N_WIRES; ++b)
            if ((mt.S[w] >> b) & 1) ct.sh[w][nb++] = (unsigned)b;
        for (; nb < 3; ++nb) ct.sh[w][nb] = 31u;           // (k>>31)&1 == 0
    }

    const int batch = in_sizes[0] / IN_DIM;

    hipLaunchKernelGGL(consts_kernel, dim3(K_BLOCKS), dim3(256), 0, stream,
                       params, wsf, ct);
    hipLaunchKernelGGL(batch_kernel, dim3(batch / ROWS_PER_BLOCK), dim3(256), 0, stream,
                       x, W, wsf, out, mt);
}

// Round 4
// 70.704 us; speedup vs baseline: 8.2752x; 1.0663x over previous
//
#include <hip/hip_runtime.h>
#include <math.h>

#define N_WIRES 12
#define DEPTH   4
#define NGATES  48
#define IN_DIM  256
#define ROWS_PER_BLOCK 16
#define XSTRIDE 272     // 256 + 16 pad

// ---- compile-time circuit structure (masks are data-independent) ----
// Gate (d,w): RX after d CNOT-chain layers; folded mask = col w of L^-d.
// L = lower-triangular ones; L^-1 = I+N (N = subdiagonal); L^-d = binomial mod 2.
// Measurement string S_w = row w of L^4 = {w, w-4, w-8} (>=0 only).
struct Tabs {
    unsigned gm[NGATES];          // gate masks
    bool     rel[N_WIRES][NGATES];// gate in G_w iff par(gm & S_w)
    unsigned chi[NGATES];         // bit i = par(gm_low_nibble & i), i=0..15
    unsigned comp[N_WIRES];       // butterfly dims = lane dims not in class
};
constexpr int cparity(unsigned v) { int c = 0; while (v) { c ^= (int)(v & 1u); v >>= 1; } return c; }
constexpr Tabs make_tabs() {
    Tabs tb{};
    for (int g = 0; g < NGATES; ++g) {
        int d = g / N_WIRES, w = g % N_WIRES;
        unsigned m = 1u << w;
        if ((d == 1 || d == 3) && w + 1 < N_WIRES) m |= 1u << (w + 1);
        if ((d == 2 || d == 3) && w + 2 < N_WIRES) m |= 1u << (w + 2);
        if (d == 3 && w + 3 < N_WIRES)             m |= 1u << (w + 3);
        tb.gm[g] = m;
        unsigned c = 0;
        for (int i = 0; i < 16; ++i) c |= (unsigned)cparity(m & 0xFu & (unsigned)i) << i;
        tb.chi[g] = c;
    }
    for (int w = 0; w < N_WIRES; ++w) {
        unsigned S = (1u << w) | (w >= 4 ? (1u << (w - 4)) : 0u) | (w >= 8 ? (1u << (w - 8)) : 0u);
        for (int g = 0; g < NGATES; ++g) tb.rel[w][g] = cparity(tb.gm[g] & S) != 0;
        unsigned lc = (w < 4) ? 0u
                    : (w < 8) ? (1u << (w - 4))
                    : ((1u << (w - 8)) | ((w - 4 < 6) ? (1u << (w - 4)) : 0u));
        tb.comp[w] = 0x3Fu & ~lc;
    }
    return tb;
}
constexpr Tabs TB = make_tabs();

// <Z_S> = 2^-n sum_k cos( P_w(k) + B_w(b,k) ); table C/D[w][kap] over k-classes
// (kap = k bits at S_w positions, ascending), computed per block (redundant,
// ~4 us, fully reg/LDS-resident); epilogue: out = (1/4096) sum_kap cosB*C - sinB*D.
__global__ __launch_bounds__(256)
void fused_kernel(const float* __restrict__ x, const float* __restrict__ W,
                  const float* __restrict__ params, float* __restrict__ out)
{
    __shared__ float xl[ROWS_PER_BLOCK * XSTRIDE];
    __shared__ float wl[N_WIRES * IN_DIM];
    __shared__ float al[ROWS_PER_BLOCK * N_WIRES];
    __shared__ float tab[N_WIRES * 16];    // [w*16 + kap] = C, [w*16+8+kap] = D
    const int t = threadIdx.x;
    const int lane = t & 63;
    const int rowbase = blockIdx.x * ROWS_PER_BLOCK;

    if (t < N_WIRES * 16) tab[t] = 0.f;

    // issue global loads early; table compute hides their latency
    const float4* x4 = (const float4*)(x + (size_t)rowbase * IN_DIM);
    float4 xr[4];
    #pragma unroll
    for (int j = 0; j < 4; ++j) xr[j] = x4[t + 256 * j];
    const float4* W4 = (const float4*)W;
    float4 wr[3];
    #pragma unroll
    for (int j = 0; j < 3; ++j) wr[j] = W4[t + 256 * j];

    __syncthreads();   // tab zero visible before atomics

    // signed thetas: fold the (k high bits = t) character sign in once
    float th[NGATES];
    #pragma unroll
    for (int g = 0; g < NGATES; ++g) {
        unsigned hs = (unsigned)(__popc((TB.gm[g] >> 4) & (unsigned)t) & 1);
        th[g] = __int_as_float(__float_as_int(params[g]) ^ (int)(hs << 31));
    }

    // fixed-part phases (gates whose mask misses k's low nibble)
    float P0[N_WIRES];
    #pragma unroll
    for (int w = 0; w < N_WIRES; ++w) {
        float p = 0.f;
        #pragma unroll
        for (int g = 0; g < NGATES; ++g)
            if (TB.rel[w][g] && (TB.gm[g] & 0xFu) == 0u) p += th[g];
        P0[w] = p;
    }

    // inner 16-k loop: compile-time signs, accumulate per (wire, low-kap-bit)
    float ca[N_WIRES][2], sa[N_WIRES][2];
    #pragma unroll
    for (int w = 0; w < N_WIRES; ++w)
        ca[w][0] = ca[w][1] = sa[w][0] = sa[w][1] = 0.f;
    #pragma unroll
    for (int i = 0; i < 16; ++i) {
        #pragma unroll
        for (int w = 0; w < N_WIRES; ++w) {
            float p = P0[w];
            #pragma unroll
            for (int g = 0; g < NGATES; ++g) {
                if (TB.rel[w][g] && (TB.gm[g] & 0xFu) != 0u) {
                    if ((TB.chi[g] >> i) & 1u) p -= th[g]; else p += th[g];
                }
            }
            float sn, cs;
            __sincosf(p, &sn, &cs);
            const int b = (i >> (w & 3)) & 1;   // kap bit0 = k bit (w&3)
            ca[w][b] += cs; sa[w][b] += sn;
        }
    }

    // butterfly over non-class lane dims, then few-lane LDS atomics
    #pragma unroll
    for (int w = 0; w < N_WIRES; ++w) {
        const unsigned comp = TB.comp[w];
        float v0c = ca[w][0], v1c = ca[w][1], v0s = sa[w][0], v1s = sa[w][1];
        #pragma unroll
        for (int d = 0; d < 6; ++d) {
            if (comp & (1u << d)) {
                v0c += __shfl_xor(v0c, 1 << d, 64);
                v1c += __shfl_xor(v1c, 1 << d, 64);
                v0s += __shfl_xor(v0s, 1 << d, 64);
                v1s += __shfl_xor(v1s, 1 << d, 64);
            }
        }
        if ((unsigned)(lane & (int)comp) == 0u) {
            unsigned fk = 0;
            if (w >= 4 && w < 8) fk = ((unsigned)t >> (w - 4)) & 1u;
            if (w >= 8) fk = (((unsigned)t >> (w - 8)) & 1u)
                           | ((((unsigned)t >> (w - 4)) & 1u) << 1);
            atomicAdd(&tab[w * 16 + (int)(fk << 1)],         v0c);
            atomicAdd(&tab[w * 16 + (int)(fk << 1) + 1],     v1c);
            atomicAdd(&tab[w * 16 + 8 + (int)(fk << 1)],     v0s);
            atomicAdd(&tab[w * 16 + 8 + (int)(fk << 1) + 1], v1s);
        }
    }

    // stage x tile + W (regs -> LDS; waits on globals here)
    #pragma unroll
    for (int j = 0; j < 4; ++j) {
        int f = t + 256 * j, row = f >> 6, c4 = f & 63;
        *(float4*)&xl[row * XSTRIDE + c4 * 4] = xr[j];
    }
    #pragma unroll
    for (int j = 0; j < 3; ++j) ((float4*)wl)[t + 256 * j] = wr[j];
    __syncthreads();

    // angles: 16 threads per row, xor-shuffle reduce
    const int r = t >> 4, p = t & 15;
    float partial[N_WIRES];
    #pragma unroll
    for (int w = 0; w < N_WIRES; ++w) partial[w] = 0.f;
    for (int i2 = 0; i2 < 16; ++i2) {
        float xv = xl[r * XSTRIDE + i2 * 16 + p];
        #pragma unroll
        for (int w = 0; w < N_WIRES; ++w)
            partial[w] = fmaf(xv, wl[w * IN_DIM + i2 * 16 + p], partial[w]);
    }
    #pragma unroll
    for (int w = 0; w < N_WIRES; ++w) {
        float v = partial[w];
        v += __shfl_xor(v, 1, 16);
        v += __shfl_xor(v, 2, 16);
        v += __shfl_xor(v, 4, 16);
        v += __shfl_xor(v, 8, 16);
        partial[w] = v;
    }
    if (p < N_WIRES) al[r * N_WIRES + p] = partial[p];
    __syncthreads();

    // epilogue: one thread per (row, wire); S_w positions are {w&3, w-4, w}
    if (t < ROWS_PER_BLOCK * N_WIRES) {
        const int r2 = t / N_WIRES;
        const int w  = t - r2 * N_WIRES;
        const int nb = 1 + (w >= 4) + (w >= 8);
        const float a0 = al[r2 * N_WIRES + (w & 3)];
        const float a1 = (w >= 4) ? al[r2 * N_WIRES + ((w >= 8) ? (w - 4) : w)] : 0.f;
        const float a2 = (w >= 8) ? al[r2 * N_WIRES + w] : 0.f;
        float o = 0.f;
        const int nk = 1 << nb;
        for (int kap = 0; kap < nk; ++kap) {
            float B = (kap & 1) ? -a0 : a0;
            if (nb > 1) B += (kap & 2) ? -a1 : a1;
            if (nb > 2) B += (kap & 4) ? -a2 : a2;
            float sn, cs;
            __sincosf(B, &sn, &cs);
            o = fmaf(cs,  tab[w * 16 + kap],     o);
            o = fmaf(-sn, tab[w * 16 + 8 + kap], o);
        }
        out[(size_t)(rowbase + r2) * N_WIRES + w] = o * (1.f / 4096.f);
    }
}

extern "C" void kernel_launch(void* const* d_in, const int* in_sizes, int n_in,
                              void* d_out, int out_size, void* d_ws, size_t ws_size,
                              hipStream_t stream) {
    const float* x      = (const float*)d_in[0];
    const float* W      = (const float*)d_in[1];
    const float* params = (const float*)d_in[2];
    float* out          = (float*)d_out;
    (void)d_ws; (void)ws_size;   // unused: avoids serializing on the ws poison fill

    const int batch = in_sizes[0] / IN_DIM;
    hipLaunchKernelGGL(fused_kernel, dim3(batch / ROWS_PER_BLOCK), dim3(256), 0, stream,
                       x, W, params, out);
}